// Round 8
// baseline (97.041 us; speedup 1.0000x reference)
//
#include <hip/hip_runtime.h>
#include <math.h>

#define S 64
#define NRES 384
#define CM 256
#define CZ 128
#define NH 8
#define CH 32
#define HC 256
#define NROW 147456   // NRES*NRES

typedef unsigned short u16;
typedef __attribute__((ext_vector_type(8))) short bf16x8;
typedef __attribute__((ext_vector_type(4))) float f32x4;
typedef __attribute__((ext_vector_type(8))) unsigned short ushort8;
typedef __attribute__((ext_vector_type(4))) unsigned short ushort4_t;

// ---- workspace byte offsets ----
#define OFF_BIAS 0            // 384 f32
#define OFF_WT   200704       // 512*256 bf16 (Wv|Wg transposed)
#define OFF_WOT  462848       // 256*256 bf16 (Wo transposed)
#define OFF_A    593920       // 8*384*384 bf16
#define OFF_VT   2953216      // [h][s][c][n] 8*64*32*384 bf16
#define OFF_G    15536128     // 24576*256 bf16
#define OFF_O    28119040     // 24576*256 bf16
#define OFF_MLN  40701952     // 24576*256 bf16 (LN(m) pre-cast)

__device__ __forceinline__ u16 f2bf(float f) {
    union { float f; unsigned int u; } v; v.f = f;
    unsigned int u = v.u;
    u += 0x7fff + ((u >> 16) & 1);
    return (u16)(u >> 16);
}
__device__ __forceinline__ float bf2f(u16 b) {
    union { float f; unsigned int u; } v; v.u = ((unsigned int)b) << 16;
    return v.f;
}
// async global->LDS, 16B per lane, dest = wave-uniform base + lane*16
__device__ __forceinline__ void gload16(const u16* g, u16* l) {
    __builtin_amdgcn_global_load_lds(
        (const __attribute__((address_space(1))) void*)g,
        (__attribute__((address_space(3))) void*)l, 16, 0, 0);
}

// =====================  misc prep: bias | Wt | Wot | mln  ====================
// blocks: [0,2) bias; [2,514) Wt; [514,770) Wot; [770,6914) m_ln
__global__ __launch_bounds__(256) void k_misc(
        const float* __restrict__ mask,
        const float* __restrict__ Wv, const float* __restrict__ Wg,
        const float* __restrict__ Wo, const float* __restrict__ m,
        const float* __restrict__ lmw, const float* __restrict__ lmb,
        float* __restrict__ bias, u16* __restrict__ Wt, u16* __restrict__ Wot,
        u16* __restrict__ mln) {
    const int bid = blockIdx.x, tid = threadIdx.x;
    if (bid < 2) {
        const int k = bid * 256 + tid;
        if (k < NRES) {
            float mx = -1e30f;
            for (int s = 0; s < S; ++s) mx = fmaxf(mx, mask[s * NRES + k]);
            bias[k] = 1e9f * (mx - 1.0f);
        }
    } else if (bid < 514) {
        const int i = (bid - 2) * 256 + tid;
        const int n = i >> 8, k = i & 255;
        const float v = (n < HC) ? Wv[(size_t)k * HC + n] : Wg[(size_t)k * HC + (n - HC)];
        Wt[i] = f2bf(v);
    } else if (bid < 770) {
        const int i = (bid - 514) * 256 + tid;
        const int n = i >> 8, k = i & 255;
        Wot[i] = f2bf(Wo[(size_t)k * CM + n]);
    } else {
        const int row = (bid - 770) * 4 + (tid >> 6);
        const int lane = tid & 63;
        const float4 x = *(const float4*)&m[(size_t)row * CM + lane * 4];
        float sm = x.x + x.y + x.z + x.w;
        float sq = x.x*x.x + x.y*x.y + x.z*x.z + x.w*x.w;
        #pragma unroll
        for (int off = 32; off >= 1; off >>= 1) {
            sm += __shfl_xor(sm, off);
            sq += __shfl_xor(sq, off);
        }
        const float mu = sm * (1.0f / CM);
        const float var = sq * (1.0f / CM) - mu * mu;
        const float rs = rsqrtf(var + 1e-5f);
        const float4 w4 = *(const float4*)&lmw[lane * 4];
        const float4 b4 = *(const float4*)&lmb[lane * 4];
        u16 t4[4];
        t4[0] = f2bf((x.x - mu) * rs * w4.x + b4.x);
        t4[1] = f2bf((x.y - mu) * rs * w4.y + b4.y);
        t4[2] = f2bf((x.z - mu) * rs * w4.z + b4.z);
        t4[3] = f2bf((x.w - mu) * rs * w4.w + b4.w);
        *(ushort4_t*)&mln[(size_t)row * CM + lane * 4] = *(ushort4_t*)t4;
    }
}

// ============  main: zbsoft (bid<384) | gemm_vg (bid>=384)  ==================
__global__ __launch_bounds__(256) void k_main(
        const float* __restrict__ z, const float* __restrict__ Wz,
        const float* __restrict__ lzw, const float* __restrict__ lzb,
        const float* __restrict__ bias,
        const u16* __restrict__ mln, const u16* __restrict__ Wt,
        u16* __restrict__ a_out, u16* __restrict__ vt, u16* __restrict__ g_) {
    __shared__ float smem[12544];   // 50,176 B
    const int bid = blockIdx.x, tid = threadIdx.x;
    const int wave = tid >> 6, lane = tid & 63;
    const int rl = lane & 15, kg = lane >> 4;

    if (bid < 384) {
        // ---------------- zb + softmax for one q ----------------
        const int q = bid;
        float* sZ   = smem;                       // [4][16*130] = 8320
        float* sLg  = smem + 8320;                // [8][392]    = 3136
        u16*  sW    = (u16*)(smem + 11456);       // [16][128]   = 1024 f32
        float* sPart = smem + 12480;              // [2][2][8]

        if (tid < 128) {
            const int c = tid;
            const float4 wz0 = *(const float4*)&Wz[c * 8];
            const float4 wz1 = *(const float4*)&Wz[c * 8 + 4];
            const float lw = lzw[c], lbv = lzb[c];
            float wzv[8] = {wz0.x, wz0.y, wz0.z, wz0.w, wz1.x, wz1.y, wz1.z, wz1.w};
            float ww[8], wb[8];
            #pragma unroll
            for (int h = 0; h < 8; ++h) {
                ww[h] = lw * wzv[h];
                wb[h] = lbv * wzv[h];
                sW[h * 128 + c] = f2bf(ww[h]);
                sW[(8 + h) * 128 + c] = 0;
            }
            #pragma unroll
            for (int h = 0; h < 8; ++h) {
                #pragma unroll
                for (int off = 1; off < 64; off <<= 1) {
                    ww[h] += __shfl_xor(ww[h], off);
                    wb[h] += __shfl_xor(wb[h], off);
                }
            }
            if (lane == 0) {
                #pragma unroll
                for (int h = 0; h < 8; ++h) {
                    sPart[wave * 16 + h]     = ww[h];
                    sPart[wave * 16 + 8 + h] = wb[h];
                }
            }
        }
        __syncthreads();
        const float c1 = (rl < 8) ? (sPart[rl] + sPart[16 + rl]) : 0.f;
        const float c2 = (rl < 8) ? (sPart[8 + rl] + sPart[24 + rl]) : 0.f;
        bf16x8 bfr[4];
        #pragma unroll
        for (int t = 0; t < 4; ++t)
            bfr[t] = *(const bf16x8*)&sW[rl * 128 + kg * 8 + t * 32];

        float* sZw = sZ + wave * 2080;            // [16][130]
        const float4* zq = (const float4*)(z + (size_t)q * NRES * CZ);
        for (int c = 0; c < 6; ++c) {
            // stage 16 rows (global rows c*64+wave*16 ..) coalesced, wave-private
            const float4* src = zq + (size_t)(c * 64 + wave * 16) * (CZ / 4);
            #pragma unroll
            for (int p = 0; p < 8; ++p) {
                const int fi = p * 64 + lane;          // float4 idx in [0,512)
                const int r = fi >> 5, c4 = fi & 31;
                *(float4*)&sZw[r * 130 + c4 * 4] = src[fi];
            }
            // frag read (f32, exact stats) + bf16 convert
            float sm = 0.f, sq = 0.f;
            bf16x8 af[4];
            #pragma unroll
            for (int t = 0; t < 4; ++t) {
                const f32x4 x0 = *(const f32x4*)&sZw[rl * 130 + t * 32 + kg * 8];
                const f32x4 x1 = *(const f32x4*)&sZw[rl * 130 + t * 32 + kg * 8 + 4];
                float xs[8] = {x0[0], x0[1], x0[2], x0[3], x1[0], x1[1], x1[2], x1[3]};
                u16 tmp[8];
                #pragma unroll
                for (int e = 0; e < 8; ++e) {
                    sm += xs[e]; sq += xs[e] * xs[e];
                    tmp[e] = f2bf(xs[e]);
                }
                af[t] = *(bf16x8*)tmp;
            }
            sm += __shfl_xor(sm, 16); sq += __shfl_xor(sq, 16);
            sm += __shfl_xor(sm, 32); sq += __shfl_xor(sq, 32);
            const float mu = sm * (1.0f / CZ);
            const float var = sq * (1.0f / CZ) - mu * mu;
            const float rs = rsqrtf(var + 1e-5f);
            f32x4 acc = {};
            #pragma unroll
            for (int t = 0; t < 4; ++t)
                acc = __builtin_amdgcn_mfma_f32_16x16x32_bf16(af[t], bfr[t], acc, 0, 0, 0);
            f32x4 pv;
            #pragma unroll
            for (int r = 0; r < 4; ++r) {
                const int rr = kg * 4 + r;
                const float mu_r = __shfl(mu, rr);
                const float rs_r = __shfl(rs, rr);
                pv[r] = rs_r * (acc[r] - mu_r * c1) + c2;
            }
            if (rl < 8)
                *(f32x4*)&sLg[rl * 392 + c * 64 + wave * 16 + kg * 4] = pv;
        }
        __syncthreads();
        // softmax: wave handles h = wave and wave+4
        #pragma unroll
        for (int hh = 0; hh < 2; ++hh) {
            const int h = wave + hh * 4;
            float v[6];
            float mx = -1e30f;
            #pragma unroll
            for (int t = 0; t < 6; ++t) {
                const int k = lane + 64 * t;
                v[t] = sLg[h * 392 + k] + bias[k];
                mx = fmaxf(mx, v[t]);
            }
            #pragma unroll
            for (int off = 32; off >= 1; off >>= 1) mx = fmaxf(mx, __shfl_xor(mx, off));
            float sum = 0.f;
            #pragma unroll
            for (int t = 0; t < 6; ++t) { v[t] = expf(v[t] - mx); sum += v[t]; }
            #pragma unroll
            for (int off = 32; off >= 1; off >>= 1) sum += __shfl_xor(sum, off);
            const float inv = 1.0f / sum;
            #pragma unroll
            for (int t = 0; t < 6; ++t)
                a_out[((size_t)h * NRES + q) * NRES + lane + 64 * t] = f2bf(v[t] * inv);
        }
        return;
    }

    // ---------------- MFMA GEMM: m_ln @ [Wv|Wg] -> vt + g ----------------
    const int bb = bid - 384;
    const int xcd = bb & 7, idx = bb >> 3;
    const int nt = idx & 3, mt = xcd * 24 + (idx >> 2);
    const int m0 = mt * 128, n0 = nt * 128;
    const int wm = (wave >> 1) * 64, wn = (wave & 1) * 64;
    const int lr = lane >> 2, lk = (lane & 3) * 8;
    const int wr = wave * 32;
    u16* As = (u16*)smem;            // [128][32]
    u16* Bs = As + 128 * 32;         // [128][32]
    const u16* ag  = mln + (size_t)(m0 + wr + lr) * CM + lk;
    const u16* ag2 = ag + 16 * CM;
    const u16* bg  = Wt + (size_t)(n0 + wr + lr) * CM + lk;
    const u16* bg2 = bg + 16 * CM;
    u16* al  = As + wr * 32;
    u16* al2 = As + (wr + 16) * 32;
    u16* bl  = Bs + wr * 32;
    u16* bl2 = Bs + (wr + 16) * 32;
    const bool vhalf = (n0 < HC);
    f32x4 acc[4][4] = {};
    for (int kt = 0; kt < CM; kt += 32) {
        if (kt) __syncthreads();
        gload16(ag + kt, al);  gload16(ag2 + kt, al2);
        gload16(bg + kt, bl);  gload16(bg2 + kt, bl2);
        __syncthreads();
        bf16x8 af[4], bfr[4];
        #pragma unroll
        for (int i = 0; i < 4; ++i) af[i]  = *(const bf16x8*)&As[(wm + i*16 + rl) * 32 + kg*8];
        #pragma unroll
        for (int j = 0; j < 4; ++j) bfr[j] = *(const bf16x8*)&Bs[(wn + j*16 + rl) * 32 + kg*8];
        if (vhalf) {
            #pragma unroll
            for (int j = 0; j < 4; ++j)
                #pragma unroll
                for (int i = 0; i < 4; ++i)
                    acc[j][i] = __builtin_amdgcn_mfma_f32_16x16x32_bf16(bfr[j], af[i], acc[j][i], 0, 0, 0);
        } else {
            #pragma unroll
            for (int i = 0; i < 4; ++i)
                #pragma unroll
                for (int j = 0; j < 4; ++j)
                    acc[i][j] = __builtin_amdgcn_mfma_f32_16x16x32_bf16(af[i], bfr[j], acc[i][j], 0, 0, 0);
        }
    }
    if (vhalf) {
        #pragma unroll
        for (int j = 0; j < 4; ++j)
            #pragma unroll
            for (int r = 0; r < 4; ++r) {
                const int vcol = n0 + wn + j*16 + kg*4 + r;
                const int h = vcol >> 5, c = vcol & 31;
                #pragma unroll
                for (int i = 0; i < 4; ++i) {
                    const int mrowb = m0 + wm + i*16;
                    const int s = mrowb / NRES;
                    const int nn = mrowb - s * NRES + rl;
                    vt[(((size_t)h * S + s) * CH + c) * NRES + nn] = f2bf(acc[j][i][r]);
                }
            }
    } else {
        #pragma unroll
        for (int i = 0; i < 4; ++i)
            #pragma unroll
            for (int r = 0; r < 4; ++r) {
                const int row = m0 + wm + i*16 + kg*4 + r;
                #pragma unroll
                for (int j = 0; j < 4; ++j) {
                    const int gc = n0 + wn + j*16 + rl - HC;
                    g_[(size_t)row * HC + gc] = f2bf(1.0f / (1.0f + expf(-acc[i][j][r])));
                }
            }
    }
}

// ========== attn as per-h GEMM (one head per XCD), gload_lds staging =========
__global__ __launch_bounds__(256) void k_attn2(const u16* __restrict__ a_,
        const u16* __restrict__ vt, u16* __restrict__ o_) {
    __shared__ u16 As[128][32];
    __shared__ u16 Bs[128][32];
    const int tid = threadIdx.x;
    const int h = blockIdx.x & 7, rem = blockIdx.x >> 3;
    const int mt = rem >> 4, nt = rem & 15;
    const int q0 = mt * 128, sc0 = nt * 128;
    const int wave = tid >> 6, lane = tid & 63;
    const int wm = (wave >> 1) * 64, wn = (wave & 1) * 64;
    const int rl = lane & 15, kg = lane >> 4;
    const int lr = lane >> 2, lk = (lane & 3) * 8;
    const int wr = wave * 32;
    const u16* ag  = a_ + (size_t)h * NRES * NRES + (size_t)(q0 + wr + lr) * NRES + lk;
    const u16* ag2 = ag + 16 * NRES;
    const u16* bg  = vt + (size_t)h * S * CH * NRES + (size_t)(sc0 + wr + lr) * NRES + lk;
    const u16* bg2 = bg + 16 * NRES;
    u16* al  = &As[wr][0];
    u16* al2 = &As[wr + 16][0];
    u16* bl  = &Bs[wr][0];
    u16* bl2 = &Bs[wr + 16][0];
    f32x4 acc[4][4] = {};
    for (int kt = 0; kt < NRES; kt += 32) {
        if (kt) __syncthreads();
        gload16(ag + kt, al);  gload16(ag2 + kt, al2);
        gload16(bg + kt, bl);  gload16(bg2 + kt, bl2);
        __syncthreads();
        bf16x8 af[4], bfr[4];
        #pragma unroll
        for (int i = 0; i < 4; ++i) af[i]  = *(const bf16x8*)&As[wm + i*16 + rl][kg*8];
        #pragma unroll
        for (int j = 0; j < 4; ++j) bfr[j] = *(const bf16x8*)&Bs[wn + j*16 + rl][kg*8];
        #pragma unroll
        for (int i = 0; i < 4; ++i)
            #pragma unroll
            for (int j = 0; j < 4; ++j)
                acc[i][j] = __builtin_amdgcn_mfma_f32_16x16x32_bf16(af[i], bfr[j], acc[i][j], 0, 0, 0);
    }
    #pragma unroll
    for (int i = 0; i < 4; ++i)
        #pragma unroll
        for (int r = 0; r < 4; ++r) {
            const int q = q0 + wm + i*16 + kg*4 + r;
            #pragma unroll
            for (int j = 0; j < 4; ++j) {
                const int sc = sc0 + wn + j*16 + rl;
                const int s = sc >> 5, c = sc & 31;
                o_[(((size_t)s * NRES + q) * NH + h) * CH + c] = f2bf(acc[i][j][r]);
            }
        }
}

// ========== out = (o*g) @ Wo  (XCD-swizzled, B via gload_lds) ================
__global__ __launch_bounds__(256) void k_gemm_out(const u16* __restrict__ o_,
        const u16* __restrict__ g_, const u16* __restrict__ Wot,
        float* __restrict__ out) {
    __shared__ u16 As[128][40];
    __shared__ u16 Bs[128][32];
    const int tid = threadIdx.x;
    const int xcd = blockIdx.x & 7, idx = blockIdx.x >> 3;
    const int nt = idx & 1, mt = xcd * 24 + (idx >> 1);
    const int m0 = mt * 128, n0 = nt * 128;
    const int wave = tid >> 6, lane = tid & 63;
    const int wm = (wave >> 1) * 64, wn = (wave & 1) * 64;
    const int rl = lane & 15, kg = lane >> 4;
    const int lr = lane >> 2, lk = (lane & 3) * 8;
    const int wr = wave * 32;
    const int sr = tid >> 1, sh = (tid & 1) * 16;
    const u16* orow = o_ + (size_t)(m0 + sr) * HC;
    const u16* grow = g_ + (size_t)(m0 + sr) * HC;
    const u16* bg  = Wot + (size_t)(n0 + wr + lr) * HC + lk;
    const u16* bg2 = bg + 16 * HC;
    u16* bl  = &Bs[wr][0];
    u16* bl2 = &Bs[wr + 16][0];
    f32x4 acc[4][4] = {};
    for (int kt = 0; kt < HC; kt += 32) {
        if (kt) __syncthreads();
        gload16(bg + kt, bl);  gload16(bg2 + kt, bl2);
        {
            u16 tmp[16];
            const ushort8 ov0 = *(const ushort8*)&orow[kt + sh];
            const ushort8 ov1 = *(const ushort8*)&orow[kt + sh + 8];
            const ushort8 gv0 = *(const ushort8*)&grow[kt + sh];
            const ushort8 gv1 = *(const ushort8*)&grow[kt + sh + 8];
            #pragma unroll
            for (int p = 0; p < 8; ++p) {
                tmp[p]     = f2bf(bf2f(ov0[p]) * bf2f(gv0[p]));
                tmp[p + 8] = f2bf(bf2f(ov1[p]) * bf2f(gv1[p]));
            }
            *(ushort8*)&As[sr][sh]     = *(ushort8*)&tmp[0];
            *(ushort8*)&As[sr][sh + 8] = *(ushort8*)&tmp[8];
        }
        __syncthreads();
        bf16x8 af[4], bfr[4];
        #pragma unroll
        for (int i = 0; i < 4; ++i) af[i]  = *(const bf16x8*)&As[wm + i*16 + rl][kg*8];
        #pragma unroll
        for (int j = 0; j < 4; ++j) bfr[j] = *(const bf16x8*)&Bs[wn + j*16 + rl][kg*8];
        #pragma unroll
        for (int i = 0; i < 4; ++i)
            #pragma unroll
            for (int j = 0; j < 4; ++j)
                acc[i][j] = __builtin_amdgcn_mfma_f32_16x16x32_bf16(af[i], bfr[j], acc[i][j], 0, 0, 0);
    }
    #pragma unroll
    for (int i = 0; i < 4; ++i)
        #pragma unroll
        for (int r = 0; r < 4; ++r) {
            const int row = m0 + wm + i*16 + kg*4 + r;
            #pragma unroll
            for (int j = 0; j < 4; ++j)
                out[(size_t)row * CM + n0 + wn + j*16 + rl] = acc[i][j][r];
        }
}

extern "C" void kernel_launch(void* const* d_in, const int* in_sizes, int n_in,
                              void* d_out, int out_size, void* d_ws, size_t ws_size,
                              hipStream_t stream) {
    const float* m      = (const float*)d_in[0];
    const float* z      = (const float*)d_in[1];
    const float* mask   = (const float*)d_in[2];
    const float* ln_m_w = (const float*)d_in[3];
    const float* ln_m_b = (const float*)d_in[4];
    const float* ln_z_w = (const float*)d_in[5];
    const float* ln_z_b = (const float*)d_in[6];
    const float* Wz     = (const float*)d_in[7];
    const float* Wv     = (const float*)d_in[8];
    const float* Wg     = (const float*)d_in[9];
    const float* Wo     = (const float*)d_in[10];
    float* out = (float*)d_out;
    char* ws = (char*)d_ws;

    float* bias = (float*)(ws + OFF_BIAS);
    u16* Wt     = (u16*)(ws + OFF_WT);
    u16* Wot    = (u16*)(ws + OFF_WOT);
    u16* a      = (u16*)(ws + OFF_A);
    u16* vtw    = (u16*)(ws + OFF_VT);
    u16* gw     = (u16*)(ws + OFF_G);
    u16* ow     = (u16*)(ws + OFF_O);
    u16* mlnw   = (u16*)(ws + OFF_MLN);

    k_misc<<<6914, 256, 0, stream>>>(mask, Wv, Wg, Wo, m, ln_m_w, ln_m_b,
                                     bias, Wt, Wot, mlnw);
    k_main<<<1152, 256, 0, stream>>>(z, Wz, ln_z_w, ln_z_b, bias, mlnw, Wt,
                                     a, vtw, gw);
    k_attn2<<<384, 256, 0, stream>>>(a, vtw, ow);
    k_gemm_out<<<384, 256, 0, stream>>>(ow, gw, Wot, out);
}

// Round 9
// 83.602 us; speedup vs baseline: 1.1607x; 1.1607x over previous
//
#include <hip/hip_runtime.h>
#include <math.h>

#define S 64
#define NRES 384
#define CM 256
#define CZ 128
#define NH 8
#define CH 32
#define HC 256
#define NROW 147456   // NRES*NRES

typedef unsigned short u16;
typedef __attribute__((ext_vector_type(8))) short bf16x8;
typedef __attribute__((ext_vector_type(4))) float f32x4;
typedef __attribute__((ext_vector_type(8))) unsigned short ushort8;
typedef __attribute__((ext_vector_type(4))) unsigned short ushort4_t;

// ---- workspace byte offsets ----
#define OFF_BIAS 0            // 384 f32
#define OFF_WT   200704       // 512*256 bf16 (Wv|Wg transposed)
#define OFF_WOT  462848       // 256*256 bf16 (Wo transposed)
#define OFF_A    593920       // 8*384*384 bf16
#define OFF_VT   2953216      // [h][s][c][n] 8*64*32*384 bf16
#define OFF_G    15536128     // 24576*256 bf16
#define OFF_O    28119040     // 24576*256 bf16
#define OFF_MLN  40701952     // 24576*256 bf16 (LN(m) pre-cast)
// overlapped (lifetimes disjoint in stream order):
#define OFF_ZB   OFF_O        // [8][147456] f32 = 4.72MB; dead before k_attn2 writes o

__device__ __forceinline__ u16 f2bf(float f) {
    union { float f; unsigned int u; } v; v.f = f;
    unsigned int u = v.u;
    u += 0x7fff + ((u >> 16) & 1);
    return (u16)(u >> 16);
}
__device__ __forceinline__ float bf2f(u16 b) {
    union { float f; unsigned int u; } v; v.u = ((unsigned int)b) << 16;
    return v.f;
}
// async global->LDS, 16B per lane, dest = wave-uniform base + lane*16
__device__ __forceinline__ void gload16(const u16* g, u16* l) {
    __builtin_amdgcn_global_load_lds(
        (const __attribute__((address_space(1))) void*)g,
        (__attribute__((address_space(3))) void*)l, 16, 0, 0);
}

// =====================  stage 1: zb | bias | Wt | Wot | mln  =================
// blocks: [0,2304) zb (64 rows each, LDS-transposed coalesced z);
//         [2304,2306) bias; [2306,2818) Wt; [2818,3074) Wot; [3074,9218) m_ln
__global__ __launch_bounds__(256) void k_stage1(
        const float* __restrict__ z, const float* __restrict__ Wz,
        const float* __restrict__ lzw, const float* __restrict__ lzb,
        const float* __restrict__ mask,
        const float* __restrict__ Wv, const float* __restrict__ Wg,
        const float* __restrict__ Wo, const float* __restrict__ m,
        const float* __restrict__ lmw, const float* __restrict__ lmb,
        float* __restrict__ zb, float* __restrict__ bias,
        u16* __restrict__ Wt, u16* __restrict__ Wot, u16* __restrict__ mln) {
    __shared__ float smem[9376];     // 37,504 B (zb branch only)
    const int bid = blockIdx.x, tid = threadIdx.x;
    if (bid < 2304) {
        float* sZ   = smem;                  // [64][130] f32 = 8320
        u16*  sW    = (u16*)(smem + 8320);   // [16][128] bf16 = 1024 f32
        float* sPart = smem + 9344;          // [2][2][8]
        const int wave = tid >> 6, lane = tid & 63;
        const int rl = lane & 15, kg = lane >> 4;
        const int row0 = bid * 64;
        // --- WWT + C1/C2 partials (2 waves) ---
        if (tid < 128) {
            const int c = tid;
            const float4 wz0 = *(const float4*)&Wz[c * 8];
            const float4 wz1 = *(const float4*)&Wz[c * 8 + 4];
            const float lw = lzw[c], lbv = lzb[c];
            float wzv[8] = {wz0.x, wz0.y, wz0.z, wz0.w, wz1.x, wz1.y, wz1.z, wz1.w};
            float ww[8], wb[8];
            #pragma unroll
            for (int h = 0; h < 8; ++h) {
                ww[h] = lw * wzv[h];
                wb[h] = lbv * wzv[h];
                sW[h * 128 + c] = f2bf(ww[h]);
                sW[(8 + h) * 128 + c] = 0;
            }
            #pragma unroll
            for (int h = 0; h < 8; ++h) {
                #pragma unroll
                for (int off = 1; off < 64; off <<= 1) {
                    ww[h] += __shfl_xor(ww[h], off);
                    wb[h] += __shfl_xor(wb[h], off);
                }
            }
            if (lane == 0) {
                #pragma unroll
                for (int h = 0; h < 8; ++h) {
                    sPart[wave * 16 + h]     = ww[h];
                    sPart[wave * 16 + 8 + h] = wb[h];
                }
            }
        }
        // --- stage 64 rows of z, fully coalesced ---
        const float4* zq = (const float4*)(z + (size_t)row0 * CZ);
        #pragma unroll
        for (int i = 0; i < 8; ++i) {
            const int fi = tid + i * 256;        // [0,2048)
            const int r = fi >> 5, c4 = fi & 31;
            *(float4*)&sZ[r * 130 + c4 * 4] = zq[fi];
        }
        __syncthreads();
        const float c1 = (rl < 8) ? (sPart[rl] + sPart[16 + rl]) : 0.f;
        const float c2 = (rl < 8) ? (sPart[8 + rl] + sPart[24 + rl]) : 0.f;
        bf16x8 bfr[4];
        #pragma unroll
        for (int t = 0; t < 4; ++t)
            bfr[t] = *(const bf16x8*)&sW[rl * 128 + kg * 8 + t * 32];
        // --- frags + exact f32 stats from LDS ---
        const float* zrow = sZ + (wave * 16 + rl) * 130 + kg * 8;
        bf16x8 af[4];
        float sm = 0.f, sq = 0.f;
        #pragma unroll
        for (int t = 0; t < 4; ++t) {
            const f32x4 x0 = *(const f32x4*)&zrow[t * 32];
            const f32x4 x1 = *(const f32x4*)&zrow[t * 32 + 4];
            float xs[8] = {x0[0], x0[1], x0[2], x0[3], x1[0], x1[1], x1[2], x1[3]};
            u16 tmp[8];
            #pragma unroll
            for (int e = 0; e < 8; ++e) {
                sm += xs[e]; sq += xs[e] * xs[e];
                tmp[e] = f2bf(xs[e]);
            }
            af[t] = *(bf16x8*)tmp;
        }
        sm += __shfl_xor(sm, 16); sq += __shfl_xor(sq, 16);
        sm += __shfl_xor(sm, 32); sq += __shfl_xor(sq, 32);
        const float mu = sm * (1.0f / CZ);
        const float var = sq * (1.0f / CZ) - mu * mu;
        const float rs = rsqrtf(var + 1e-5f);
        f32x4 acc = {};
        #pragma unroll
        for (int t = 0; t < 4; ++t)
            acc = __builtin_amdgcn_mfma_f32_16x16x32_bf16(af[t], bfr[t], acc, 0, 0, 0);
        f32x4 pv;
        #pragma unroll
        for (int r = 0; r < 4; ++r) {
            const int rr = kg * 4 + r;
            const float mu_r = __shfl(mu, rr);
            const float rs_r = __shfl(rs, rr);
            pv[r] = rs_r * (acc[r] - mu_r * c1) + c2;
        }
        if (rl < 8)
            *(f32x4*)&zb[(size_t)rl * NROW + row0 + wave * 16 + kg * 4] = pv;
    } else if (bid < 2306) {
        const int k = (bid - 2304) * 256 + tid;
        if (k < NRES) {
            float mx = -1e30f;
            for (int s = 0; s < S; ++s) mx = fmaxf(mx, mask[s * NRES + k]);
            bias[k] = 1e9f * (mx - 1.0f);
        }
    } else if (bid < 2818) {
        const int i = (bid - 2306) * 256 + tid;
        const int n = i >> 8, k = i & 255;
        const float v = (n < HC) ? Wv[(size_t)k * HC + n] : Wg[(size_t)k * HC + (n - HC)];
        Wt[i] = f2bf(v);
    } else if (bid < 3074) {
        const int i = (bid - 2818) * 256 + tid;
        const int n = i >> 8, k = i & 255;
        Wot[i] = f2bf(Wo[(size_t)k * CM + n]);
    } else {
        const int row = (bid - 3074) * 4 + (tid >> 6);
        const int lane = tid & 63;
        const float4 x = *(const float4*)&m[(size_t)row * CM + lane * 4];
        float sm = x.x + x.y + x.z + x.w;
        float sq = x.x*x.x + x.y*x.y + x.z*x.z + x.w*x.w;
        #pragma unroll
        for (int off = 32; off >= 1; off >>= 1) {
            sm += __shfl_xor(sm, off);
            sq += __shfl_xor(sq, off);
        }
        const float mu = sm * (1.0f / CM);
        const float var = sq * (1.0f / CM) - mu * mu;
        const float rs = rsqrtf(var + 1e-5f);
        const float4 w4 = *(const float4*)&lmw[lane * 4];
        const float4 b4 = *(const float4*)&lmb[lane * 4];
        u16 t4[4];
        t4[0] = f2bf((x.x - mu) * rs * w4.x + b4.x);
        t4[1] = f2bf((x.y - mu) * rs * w4.y + b4.y);
        t4[2] = f2bf((x.z - mu) * rs * w4.z + b4.z);
        t4[3] = f2bf((x.w - mu) * rs * w4.w + b4.w);
        *(ushort4_t*)&mln[(size_t)row * CM + lane * 4] = *(ushort4_t*)t4;
    }
}

// =====================  stage 2: gemm_vg | soft  =============================
// blocks: [0,768) gemm_vg (XCD-swizzled); [768,1536) softmax
__global__ __launch_bounds__(256) void k_stage2(
        const u16* __restrict__ mln, const u16* __restrict__ Wt,
        const float* __restrict__ zb, const float* __restrict__ bias,
        u16* __restrict__ vt, u16* __restrict__ g_, u16* __restrict__ a_out) {
    __shared__ u16 As[128][32];
    __shared__ u16 Bs[128][32];
    const int bid = blockIdx.x, tid = threadIdx.x;
    if (bid >= 768) {
        // ---- softmax over k (coalesced zb[h][q*384+k] reads) ----
        const int w = (bid - 768) * 4 + (tid >> 6);
        const int lane = tid & 63;
        const int h = w & 7, q = w >> 3;
        const float* zbh = zb + (size_t)h * NROW + (size_t)q * NRES;
        float v[6];
        float mx = -1e30f;
        #pragma unroll
        for (int t = 0; t < 6; ++t) {
            const int k = lane + 64 * t;
            v[t] = zbh[k] + bias[k];
            mx = fmaxf(mx, v[t]);
        }
        #pragma unroll
        for (int off = 32; off >= 1; off >>= 1) mx = fmaxf(mx, __shfl_xor(mx, off));
        float sum = 0.f;
        #pragma unroll
        for (int t = 0; t < 6; ++t) { v[t] = expf(v[t] - mx); sum += v[t]; }
        #pragma unroll
        for (int off = 32; off >= 1; off >>= 1) sum += __shfl_xor(sum, off);
        const float inv = 1.0f / sum;
        #pragma unroll
        for (int t = 0; t < 6; ++t)
            a_out[((size_t)h * NRES + q) * NRES + lane + 64 * t] = f2bf(v[t] * inv);
        return;
    }
    // ---- MFMA GEMM: m_ln @ [Wv|Wg] -> vt + g, gload_lds staging ----
    const int xcd = bid & 7, idx = bid >> 3;
    const int nt = idx & 3, mt = xcd * 24 + (idx >> 2);
    const int m0 = mt * 128, n0 = nt * 128;
    const int wave = tid >> 6, lane = tid & 63;
    const int wm = (wave >> 1) * 64, wn = (wave & 1) * 64;
    const int rl = lane & 15, kg = lane >> 4;
    const int lr = lane >> 2, lk = (lane & 3) * 8;
    const int wr = wave * 32;
    const u16* ag  = mln + (size_t)(m0 + wr + lr) * CM + lk;
    const u16* ag2 = ag + 16 * CM;
    const u16* bg  = Wt + (size_t)(n0 + wr + lr) * CM + lk;
    const u16* bg2 = bg + 16 * CM;
    u16* al  = &As[wr][0];
    u16* al2 = &As[wr + 16][0];
    u16* bl  = &Bs[wr][0];
    u16* bl2 = &Bs[wr + 16][0];
    const bool vhalf = (n0 < HC);
    f32x4 acc[4][4] = {};
    for (int kt = 0; kt < CM; kt += 32) {
        if (kt) __syncthreads();
        gload16(ag + kt, al);  gload16(ag2 + kt, al2);
        gload16(bg + kt, bl);  gload16(bg2 + kt, bl2);
        __syncthreads();
        bf16x8 af[4], bfr[4];
        #pragma unroll
        for (int i = 0; i < 4; ++i) af[i]  = *(const bf16x8*)&As[wm + i*16 + rl][kg*8];
        #pragma unroll
        for (int j = 0; j < 4; ++j) bfr[j] = *(const bf16x8*)&Bs[wn + j*16 + rl][kg*8];
        if (vhalf) {
            #pragma unroll
            for (int j = 0; j < 4; ++j)
                #pragma unroll
                for (int i = 0; i < 4; ++i)
                    acc[j][i] = __builtin_amdgcn_mfma_f32_16x16x32_bf16(bfr[j], af[i], acc[j][i], 0, 0, 0);
        } else {
            #pragma unroll
            for (int i = 0; i < 4; ++i)
                #pragma unroll
                for (int j = 0; j < 4; ++j)
                    acc[i][j] = __builtin_amdgcn_mfma_f32_16x16x32_bf16(af[i], bfr[j], acc[i][j], 0, 0, 0);
        }
    }
    if (vhalf) {
        #pragma unroll
        for (int j = 0; j < 4; ++j)
            #pragma unroll
            for (int r = 0; r < 4; ++r) {
                const int vcol = n0 + wn + j*16 + kg*4 + r;
                const int h = vcol >> 5, c = vcol & 31;
                #pragma unroll
                for (int i = 0; i < 4; ++i) {
                    const int mrowb = m0 + wm + i*16;
                    const int s = mrowb / NRES;
                    const int nn = mrowb - s * NRES + rl;
                    vt[(((size_t)h * S + s) * CH + c) * NRES + nn] = f2bf(acc[j][i][r]);
                }
            }
    } else {
        #pragma unroll
        for (int i = 0; i < 4; ++i)
            #pragma unroll
            for (int r = 0; r < 4; ++r) {
                const int row = m0 + wm + i*16 + kg*4 + r;
                #pragma unroll
                for (int j = 0; j < 4; ++j) {
                    const int gc = n0 + wn + j*16 + rl - HC;
                    g_[(size_t)row * HC + gc] = f2bf(1.0f / (1.0f + expf(-acc[i][j][r])));
                }
            }
    }
}

// ========== attn as per-h GEMM (one head per XCD), gload_lds staging =========
__global__ __launch_bounds__(256) void k_attn2(const u16* __restrict__ a_,
        const u16* __restrict__ vt, u16* __restrict__ o_) {
    __shared__ u16 As[128][32];
    __shared__ u16 Bs[128][32];
    const int tid = threadIdx.x;
    const int h = blockIdx.x & 7, rem = blockIdx.x >> 3;
    const int mt = rem >> 4, nt = rem & 15;
    const int q0 = mt * 128, sc0 = nt * 128;
    const int wave = tid >> 6, lane = tid & 63;
    const int wm = (wave >> 1) * 64, wn = (wave & 1) * 64;
    const int rl = lane & 15, kg = lane >> 4;
    const int lr = lane >> 2, lk = (lane & 3) * 8;
    const int wr = wave * 32;
    const u16* ag  = a_ + (size_t)h * NRES * NRES + (size_t)(q0 + wr + lr) * NRES + lk;
    const u16* ag2 = ag + 16 * NRES;
    const u16* bg  = vt + (size_t)h * S * CH * NRES + (size_t)(sc0 + wr + lr) * NRES + lk;
    const u16* bg2 = bg + 16 * NRES;
    u16* al  = &As[wr][0];
    u16* al2 = &As[wr + 16][0];
    u16* bl  = &Bs[wr][0];
    u16* bl2 = &Bs[wr + 16][0];
    f32x4 acc[4][4] = {};
    for (int kt = 0; kt < NRES; kt += 32) {
        if (kt) __syncthreads();
        gload16(ag + kt, al);  gload16(ag2 + kt, al2);
        gload16(bg + kt, bl);  gload16(bg2 + kt, bl2);
        __syncthreads();
        bf16x8 af[4], bfr[4];
        #pragma unroll
        for (int i = 0; i < 4; ++i) af[i]  = *(const bf16x8*)&As[wm + i*16 + rl][kg*8];
        #pragma unroll
        for (int j = 0; j < 4; ++j) bfr[j] = *(const bf16x8*)&Bs[wn + j*16 + rl][kg*8];
        #pragma unroll
        for (int i = 0; i < 4; ++i)
            #pragma unroll
            for (int j = 0; j < 4; ++j)
                acc[i][j] = __builtin_amdgcn_mfma_f32_16x16x32_bf16(af[i], bfr[j], acc[i][j], 0, 0, 0);
    }
    #pragma unroll
    for (int i = 0; i < 4; ++i)
        #pragma unroll
        for (int r = 0; r < 4; ++r) {
            const int q = q0 + wm + i*16 + kg*4 + r;
            #pragma unroll
            for (int j = 0; j < 4; ++j) {
                const int sc = sc0 + wn + j*16 + rl;
                const int s = sc >> 5, c = sc & 31;
                o_[(((size_t)s * NRES + q) * NH + h) * CH + c] = f2bf(acc[i][j][r]);
            }
        }
}

// ========== out = (o*g) @ Wo  (XCD-swizzled, B via gload_lds) ================
__global__ __launch_bounds__(256) void k_gemm_out(const u16* __restrict__ o_,
        const u16* __restrict__ g_, const u16* __restrict__ Wot,
        float* __restrict__ out) {
    __shared__ u16 As[128][40];
    __shared__ u16 Bs[128][32];
    const int tid = threadIdx.x;
    const int xcd = blockIdx.x & 7, idx = blockIdx.x >> 3;
    const int nt = idx & 1, mt = xcd * 24 + (idx >> 1);
    const int m0 = mt * 128, n0 = nt * 128;
    const int wave = tid >> 6, lane = tid & 63;
    const int wm = (wave >> 1) * 64, wn = (wave & 1) * 64;
    const int rl = lane & 15, kg = lane >> 4;
    const int lr = lane >> 2, lk = (lane & 3) * 8;
    const int wr = wave * 32;
    const int sr = tid >> 1, sh = (tid & 1) * 16;
    const u16* orow = o_ + (size_t)(m0 + sr) * HC;
    const u16* grow = g_ + (size_t)(m0 + sr) * HC;
    const u16* bg  = Wot + (size_t)(n0 + wr + lr) * HC + lk;
    const u16* bg2 = bg + 16 * HC;
    u16* bl  = &Bs[wr][0];
    u16* bl2 = &Bs[wr + 16][0];
    f32x4 acc[4][4] = {};
    for (int kt = 0; kt < HC; kt += 32) {
        if (kt) __syncthreads();
        gload16(bg + kt, bl);  gload16(bg2 + kt, bl2);
        {
            u16 tmp[16];
            const ushort8 ov0 = *(const ushort8*)&orow[kt + sh];
            const ushort8 ov1 = *(const ushort8*)&orow[kt + sh + 8];
            const ushort8 gv0 = *(const ushort8*)&grow[kt + sh];
            const ushort8 gv1 = *(const ushort8*)&grow[kt + sh + 8];
            #pragma unroll
            for (int p = 0; p < 8; ++p) {
                tmp[p]     = f2bf(bf2f(ov0[p]) * bf2f(gv0[p]));
                tmp[p + 8] = f2bf(bf2f(ov1[p]) * bf2f(gv1[p]));
            }
            *(ushort8*)&As[sr][sh]     = *(ushort8*)&tmp[0];
            *(ushort8*)&As[sr][sh + 8] = *(ushort8*)&tmp[8];
        }
        __syncthreads();
        bf16x8 af[4], bfr[4];
        #pragma unroll
        for (int i = 0; i < 4; ++i) af[i]  = *(const bf16x8*)&As[wm + i*16 + rl][kg*8];
        #pragma unroll
        for (int j = 0; j < 4; ++j) bfr[j] = *(const bf16x8*)&Bs[wn + j*16 + rl][kg*8];
        #pragma unroll
        for (int i = 0; i < 4; ++i)
            #pragma unroll
            for (int j = 0; j < 4; ++j)
                acc[i][j] = __builtin_amdgcn_mfma_f32_16x16x32_bf16(af[i], bfr[j], acc[i][j], 0, 0, 0);
    }
    #pragma unroll
    for (int i = 0; i < 4; ++i)
        #pragma unroll
        for (int r = 0; r < 4; ++r) {
            const int row = m0 + wm + i*16 + kg*4 + r;
            #pragma unroll
            for (int j = 0; j < 4; ++j)
                out[(size_t)row * CM + n0 + wn + j*16 + rl] = acc[i][j][r];
        }
}

extern "C" void kernel_launch(void* const* d_in, const int* in_sizes, int n_in,
                              void* d_out, int out_size, void* d_ws, size_t ws_size,
                              hipStream_t stream) {
    const float* m      = (const float*)d_in[0];
    const float* z      = (const float*)d_in[1];
    const float* mask   = (const float*)d_in[2];
    const float* ln_m_w = (const float*)d_in[3];
    const float* ln_m_b = (const float*)d_in[4];
    const float* ln_z_w = (const float*)d_in[5];
    const float* ln_z_b = (const float*)d_in[6];
    const float* Wz     = (const float*)d_in[7];
    const float* Wv     = (const float*)d_in[8];
    const float* Wg     = (const float*)d_in[9];
    const float* Wo     = (const float*)d_in[10];
    float* out = (float*)d_out;
    char* ws = (char*)d_ws;

    float* bias = (float*)(ws + OFF_BIAS);
    u16* Wt     = (u16*)(ws + OFF_WT);
    u16* Wot    = (u16*)(ws + OFF_WOT);
    u16* a      = (u16*)(ws + OFF_A);
    u16* vtw    = (u16*)(ws + OFF_VT);
    u16* gw     = (u16*)(ws + OFF_G);
    u16* ow     = (u16*)(ws + OFF_O);
    u16* mlnw   = (u16*)(ws + OFF_MLN);
    float* zbw  = (float*)(ws + OFF_ZB);

    k_stage1<<<9218, 256, 0, stream>>>(z, Wz, ln_z_w, ln_z_b, mask, Wv, Wg, Wo,
                                       m, ln_m_w, ln_m_b, zbw, bias, Wt, Wot, mlnw);
    k_stage2<<<1536, 256, 0, stream>>>(mlnw, Wt, zbw, bias, vtw, gw, a);
    k_attn2<<<384, 256, 0, stream>>>(a, vtw, ow);
    k_gemm_out<<<384, 256, 0, stream>>>(ow, gw, Wot, out);
}